// Round 19
// baseline (140.499 us; speedup 1.0000x reference)
//
#include <hip/hip_runtime.h>
#include <hip/hip_bf16.h>
#include <stdint.h>

typedef __attribute__((ext_vector_type(4))) float f32x4;
typedef __attribute__((ext_vector_type(8))) __bf16 bf16x8;
typedef __attribute__((ext_vector_type(4))) unsigned short us4;
typedef __attribute__((ext_vector_type(8))) unsigned short us8;

#define SEQ 2048
#define DMODEL 1024
#define NH 16
#define DK 64
#define MTOT 4096  // B*SEQ

__device__ __forceinline__ unsigned short f2bf(float x) {
  union { float f; unsigned int u; } v; v.f = x;
  unsigned int r = v.u + 0x7fffu + ((v.u >> 16) & 1u);
  return (unsigned short)(r >> 16);
}

// pack 2 f32 -> 2 bf16 in one u32 (lo, hi)
__device__ __forceinline__ unsigned int cvtpk(float lo, float hi) {
  unsigned int r;
  asm("v_cvt_pk_bf16_f32 %0, %1, %2" : "=v"(r) : "v"(lo), "v"(hi));
  return r;
}

__device__ __forceinline__ f32x4 mfma_bf16(bf16x8 a, bf16x8 b, f32x4 c) {
  return __builtin_amdgcn_mfma_f32_16x16x32_bf16(a, b, c, 0, 0, 0);
}

__device__ __forceinline__ void gload16(const unsigned short* g, unsigned short* l) {
  __builtin_amdgcn_global_load_lds((__attribute__((address_space(1))) void*)g,
                                   (__attribute__((address_space(3))) void*)l,
                                   16, 0, 0);
}

// ---------------- fp32 -> bf16 conversion (weights only) ----------------
__global__ void cvt_w(const float* __restrict__ s0, const float* __restrict__ s1,
                      const float* __restrict__ s2, const float* __restrict__ s3,
                      unsigned short* __restrict__ d0, unsigned short* __restrict__ d1,
                      unsigned short* __restrict__ d2, unsigned short* __restrict__ d3) {
  const int y = blockIdx.y;
  const float* s = y == 0 ? s0 : y == 1 ? s1 : y == 2 ? s2 : s3;
  unsigned short* d = y == 0 ? d0 : y == 1 ? d1 : y == 2 ? d2 : d3;
  const int n4 = DMODEL * DMODEL / 4;
  const int stride = gridDim.x * blockDim.x;
  for (int i = blockIdx.x * blockDim.x + threadIdx.x; i < n4; i += stride) {
    f32x4 v = reinterpret_cast<const f32x4*>(s)[i];
    us4 o;
    o.x = f2bf(v.x); o.y = f2bf(v.y); o.z = f2bf(v.z); o.w = f2bf(v.w);
    reinterpret_cast<us4*>(d)[i] = o;
  }
}

// ---------------- Q/K GEMM: BK=64 (half the barriers), fused f32 A, XOR-8 LDS ----------
// C[m,n] = sum_k A[m,k]*B[n,k]; swapped epilogue -> head layout [bh][s][64] bf16,
// 8B packed stores. LDS rows are 128B: slot pos of row holds logical chunk
// pos^(row&7) -> both ds_write (A) and b128 reads are 2-way (free).
__global__ __launch_bounds__(256) void gemm_qk(
    const float* __restrict__ xq, const float* __restrict__ xk,
    const unsigned short* __restrict__ bwq, const unsigned short* __restrict__ bwk,
    unsigned short* __restrict__ Qh, unsigned short* __restrict__ Kh) {
  const int z = blockIdx.z;
  const float* A = z ? xk : xq;
  const unsigned short* B = z ? bwk : bwq;
  unsigned short* out = z ? Kh : Qh;
  const float scale = z ? 1.0f : 0.18033688011112042f;  // (1/8)*log2(e) for Q

  __shared__ __align__(16) unsigned short lA[128 * 64];  // 16KB
  __shared__ __align__(16) unsigned short lB[128 * 64];  // 16KB
  const int tid = threadIdx.x;
  const int lane = tid & 63;
  const int wid = tid >> 6;
  const int l15 = lane & 15, l4 = lane >> 4;
  const int bm = blockIdx.x, bn = blockIdx.y;
  const int wr = wid >> 1, wc = wid & 1;

  f32x4 acc[4][4] = {};

  // ---- A staging: thread -> row ar = tid>>1, col-half h = tid&1 (32 f32) ----
  const int ar = tid >> 1, h = tid & 1;
  const float* gAf = A + (size_t)(bm * 128 + ar) * 1024 + h * 32;
  const int arx = ar & 7;
  unsigned short* wA = lA + ar * 64;

  // ---- B staging: 4 gload_lds issues, pre-swizzled source ----
  const unsigned short* gBs[4];
  unsigned short* lBd[4];
#pragma unroll
  for (int is = 0; is < 4; ++is) {
    const int G = is * 256 + tid;
    const int row = G >> 3, pp = G & 7;
    const int lg = pp ^ (row & 7);
    gBs[is] = B + (size_t)(bn * 128 + row) * 1024 + lg * 8;
    lBd[is] = lB + (is * 256 + wid * 64) * 8;  // wave-uniform; HW adds lane*16B
  }

  f32x4 arg[8];
#define QK_LOADA(kt_)                                                     \
  {                                                                       \
    _Pragma("unroll")                                                     \
    for (int jj = 0; jj < 8; ++jj)                                        \
      arg[jj] = *reinterpret_cast<const f32x4*>(gAf + (kt_) + jj * 4);    \
  }

  QK_LOADA(0);

#pragma unroll 1
  for (int kt = 0; kt < 1024; kt += 64) {
    __syncthreads();  // prev iteration's LDS readers done
#pragma unroll
    for (int j = 0; j < 4; ++j) {
      union { us8 v; unsigned int u[4]; } w;
      w.u[0] = cvtpk(arg[2 * j][0], arg[2 * j][1]);
      w.u[1] = cvtpk(arg[2 * j][2], arg[2 * j][3]);
      w.u[2] = cvtpk(arg[2 * j + 1][0], arg[2 * j + 1][1]);
      w.u[3] = cvtpk(arg[2 * j + 1][2], arg[2 * j + 1][3]);
      const int pos = (h * 4 + j) ^ arx;
      *reinterpret_cast<us8*>(wA + pos * 8) = w.v;
    }
#pragma unroll
    for (int is = 0; is < 4; ++is) gload16(gBs[is] + kt, lBd[is]);
    __syncthreads();  // staging visible (compiler drains vmcnt/lgkmcnt)

    // next tile's A loads issued AFTER the barrier: 32 MFMA hide their latency
    if (kt + 64 < 1024) QK_LOADA(kt + 64);

#pragma unroll
    for (int kk = 0; kk < 2; ++kk) {
      bf16x8 af[4], bfr[4];
#pragma unroll
      for (int i = 0; i < 4; ++i) {
        const int row = wr * 64 + i * 16 + l15;
        af[i] = *reinterpret_cast<const bf16x8*>(
            &lA[row * 64 + (((kk * 4 + l4) ^ (l15 & 7)) * 8)]);
      }
#pragma unroll
      for (int j = 0; j < 4; ++j) {
        const int row = wc * 64 + j * 16 + l15;
        bfr[j] = *reinterpret_cast<const bf16x8*>(
            &lB[row * 64 + (((kk * 4 + l4) ^ (l15 & 7)) * 8)]);
      }
#pragma unroll
      for (int i = 0; i < 4; ++i)
#pragma unroll
        for (int j = 0; j < 4; ++j)
          acc[i][j] = mfma_bf16(bfr[j], af[i], acc[i][j]);  // SWAPPED: 4 consec n/lane
    }
  }
#undef QK_LOADA

  const int row0 = bm * 128 + wr * 64;
  const int col0 = bn * 128 + wc * 64;
#pragma unroll
  for (int i = 0; i < 4; ++i) {
    const int m = row0 + i * 16 + l15;
    const int b = m >> 11, s = m & 2047;
#pragma unroll
    for (int j = 0; j < 4; ++j) {
      const int n0 = col0 + j * 16 + l4 * 4;
      const int hh = n0 >> 6, dd = n0 & 63;
      union { us4 h4; unsigned int u[2]; } pk;
      pk.u[0] = cvtpk(acc[i][j][0] * scale, acc[i][j][1] * scale);
      pk.u[1] = cvtpk(acc[i][j][2] * scale, acc[i][j][3] * scale);
      *reinterpret_cast<us4*>(&out[(size_t)(b * NH + hh) * (SEQ * DK) + s * DK + dd]) = pk.h4;
    }
  }
}

// ---------------- V GEMM: BK=64 body, V^T PV-permuted epilogue ----------------
__global__ __launch_bounds__(256) void gemm_v(
    const float* __restrict__ xv, const unsigned short* __restrict__ bwv,
    unsigned short* __restrict__ Vt) {
  __shared__ __align__(16) unsigned short lA[128 * 64];
  __shared__ __align__(16) unsigned short lB[128 * 64];
  const int tid = threadIdx.x;
  const int lane = tid & 63;
  const int wid = tid >> 6;
  const int l15 = lane & 15, l4 = lane >> 4;
  const int bm = blockIdx.x, bn = blockIdx.y;
  const int wr = wid >> 1, wc = wid & 1;

  f32x4 acc[4][4] = {};

  const int ar = tid >> 1, h = tid & 1;
  const float* gAf = xv + (size_t)(bm * 128 + ar) * 1024 + h * 32;
  const int arx = ar & 7;
  unsigned short* wA = lA + ar * 64;

  const unsigned short* gBs[4];
  unsigned short* lBd[4];
#pragma unroll
  for (int is = 0; is < 4; ++is) {
    const int G = is * 256 + tid;
    const int row = G >> 3, pp = G & 7;
    const int lg = pp ^ (row & 7);
    gBs[is] = bwv + (size_t)(bn * 128 + row) * 1024 + lg * 8;
    lBd[is] = lB + (is * 256 + wid * 64) * 8;
  }

  f32x4 arg[8];
#define V_LOADA(kt_)                                                      \
  {                                                                       \
    _Pragma("unroll")                                                     \
    for (int jj = 0; jj < 8; ++jj)                                        \
      arg[jj] = *reinterpret_cast<const f32x4*>(gAf + (kt_) + jj * 4);    \
  }

  V_LOADA(0);

#pragma unroll 1
  for (int kt = 0; kt < 1024; kt += 64) {
    __syncthreads();
#pragma unroll
    for (int j = 0; j < 4; ++j) {
      union { us8 v; unsigned int u[4]; } w;
      w.u[0] = cvtpk(arg[2 * j][0], arg[2 * j][1]);
      w.u[1] = cvtpk(arg[2 * j][2], arg[2 * j][3]);
      w.u[2] = cvtpk(arg[2 * j + 1][0], arg[2 * j + 1][1]);
      w.u[3] = cvtpk(arg[2 * j + 1][2], arg[2 * j + 1][3]);
      const int pos = (h * 4 + j) ^ arx;
      *reinterpret_cast<us8*>(wA + pos * 8) = w.v;
    }
#pragma unroll
    for (int is = 0; is < 4; ++is) gload16(gBs[is] + kt, lBd[is]);
    __syncthreads();

    if (kt + 64 < 1024) V_LOADA(kt + 64);

#pragma unroll
    for (int kk = 0; kk < 2; ++kk) {
      bf16x8 af[4], bfr[4];
#pragma unroll
      for (int i = 0; i < 4; ++i) {
        const int row = wr * 64 + i * 16 + l15;
        af[i] = *reinterpret_cast<const bf16x8*>(
            &lA[row * 64 + (((kk * 4 + l4) ^ (l15 & 7)) * 8)]);
      }
#pragma unroll
      for (int j = 0; j < 4; ++j) {
        const int row = wc * 64 + j * 16 + l15;
        bfr[j] = *reinterpret_cast<const bf16x8*>(
            &lB[row * 64 + (((kk * 4 + l4) ^ (l15 & 7)) * 8)]);
      }
#pragma unroll
      for (int i = 0; i < 4; ++i)
#pragma unroll
        for (int j = 0; j < 4; ++j)
          acc[i][j] = mfma_bf16(af[i], bfr[j], acc[i][j]);  // unswapped: 4 consec m/lane
    }
  }
#undef V_LOADA

  const int row0 = bm * 128 + wr * 64;
  const int col0 = bn * 128 + wc * 64;
  // V^T with per-32-col PV permutation: 4-group g of each 32-chunk stored at
  // (g&3)*8 + (g>>2)*4 so attn's b128 read yields a legal K=32 fragment.
#pragma unroll
  for (int i = 0; i < 4; ++i) {
    const int m0 = row0 + i * 16 + l4 * 4;
    const int b = m0 >> 11, s0 = m0 & 2047;
    const int g = (s0 >> 2) & 7;
    const int col = (s0 & ~31) + ((g & 3) << 3) + ((g >> 2) << 2);
#pragma unroll
    for (int j = 0; j < 4; ++j) {
      const int n = col0 + j * 16 + l15;
      const int hh = n >> 6, dd = n & 63;
      union { us4 h4; unsigned int u[2]; } pk;
      pk.u[0] = cvtpk(acc[i][j][0], acc[i][j][1]);
      pk.u[1] = cvtpk(acc[i][j][2], acc[i][j][3]);
      *reinterpret_cast<us4*>(&Vt[(size_t)(b * NH + hh) * (DK * SEQ) + dd * SEQ + col]) = pk.h4;
    }
  }
}

// ---------------- output-projection GEMM: 8 waves, BK=64, 3-buffer pipeline ----------------
__global__ __launch_bounds__(512) void gemm_o(const unsigned short* __restrict__ A,
                                              const unsigned short* __restrict__ B,
                                              float* __restrict__ out) {
  __shared__ __align__(16) unsigned short lA3[3][128 * 64];
  __shared__ __align__(16) unsigned short lB3[3][128 * 64];

  const int tid = threadIdx.x;
  const int lane = tid & 63, wid = tid >> 6;
  const int l15 = lane & 15, l4 = lane >> 4;
  const int bm = blockIdx.x, bn = blockIdx.y;
  const int wr = wid >> 1, wc = wid & 1;

  f32x4 acc[2][4] = {};

  const int r8 = lane >> 3, c8 = lane & 7;
  const unsigned short* gAs[2];
  const unsigned short* gBs[2];
  int dstoff[2];
#pragma unroll
  for (int is = 0; is < 2; ++is) {
    const int rbase = is * 64 + wid * 8;
    gAs[is] = A + (size_t)(bm * 128 + rbase + r8) * 1024 + (c8 ^ r8) * 8;
    gBs[is] = B + (size_t)(bn * 128 + rbase + r8) * 1024 + (c8 ^ r8) * 8;
    dstoff[is] = rbase * 64;
  }

#define STAGE_O(t, buf)                                         \
  {                                                             \
    const int kb = (t) * 64;                                    \
    gload16(gAs[0] + kb, &lA3[buf][dstoff[0]]);                 \
    gload16(gAs[1] + kb, &lA3[buf][dstoff[1]]);                 \
    gload16(gBs[0] + kb, &lB3[buf][dstoff[0]]);                 \
    gload16(gBs[1] + kb, &lB3[buf][dstoff[1]]);                 \
  }

  STAGE_O(0, 0);
  STAGE_O(1, 1);

#pragma unroll 1
  for (int t = 0; t < 16; ++t) {
    if (t + 1 < 16) {
      asm volatile("s_waitcnt vmcnt(4)" ::: "memory");
    } else {
      asm volatile("s_waitcnt vmcnt(0)" ::: "memory");
    }
    __builtin_amdgcn_sched_barrier(0);
    __builtin_amdgcn_s_barrier();
    __builtin_amdgcn_sched_barrier(0);

    if (t + 2 < 16) {
      const int pb = (t + 2) % 3;
      STAGE_O(t + 2, pb);
    }

    const unsigned short* La = lA3[t % 3];
    const unsigned short* Lb = lB3[t % 3];
#pragma unroll
    for (int kk = 0; kk < 2; ++kk) {
      bf16x8 af[2], bf[4];
#pragma unroll
      for (int i = 0; i < 2; ++i) {
        const int row = wr * 32 + i * 16 + l15;
        af[i] = *reinterpret_cast<const bf16x8*>(
            &La[row * 64 + (((kk * 4 + l4) ^ (l15 & 7)) * 8)]);
      }
#pragma unroll
      for (int j = 0; j < 4; ++j) {
        const int row = wc * 64 + j * 16 + l15;
        bf[j] = *reinterpret_cast<const bf16x8*>(
            &Lb[row * 64 + (((kk * 4 + l4) ^ (l15 & 7)) * 8)]);
      }
#pragma unroll
      for (int i = 0; i < 2; ++i)
#pragma unroll
        for (int j = 0; j < 4; ++j)
          acc[i][j] = mfma_bf16(bf[j], af[i], acc[i][j]);  // SWAPPED
    }
  }
#undef STAGE_O

  const int row0 = bm * 128 + wr * 32;
  const int col0 = bn * 128 + wc * 64;
#pragma unroll
  for (int i = 0; i < 2; ++i) {
    const int m = row0 + i * 16 + l15;
#pragma unroll
    for (int j = 0; j < 4; ++j) {
      const int n0 = col0 + j * 16 + l4 * 4;
      *reinterpret_cast<f32x4*>(&out[(size_t)m * DMODEL + n0]) = acc[i][j];
    }
  }
}

// ---------------- causal flash attention v9: 512 blocks, balanced split-pair ----------------
__global__ __launch_bounds__(512, 2) void attn_kernel(const unsigned short* __restrict__ Qh,
                                                      const unsigned short* __restrict__ Kh,
                                                      const unsigned short* __restrict__ Vt,
                                                      unsigned short* __restrict__ Mg) {
  __shared__ __align__(16) unsigned short Kl[4][64 * 64];
  __shared__ __align__(16) unsigned short Vl[4][64 * 64];

  const int tid = threadIdx.x;
  const int lane = tid & 63;
  const int w = tid >> 6;
  const int l15 = lane & 15, l4 = lane >> 4;

  const int d = blockIdx.x;            // 0..511
  const int base = d & 255;            // CU slot (round-robin assumption)
  const int pair = d >> 8;             // 0: long tile, 1: short tile
  const int xcd = base & 7;
  const int jj = base >> 3;            // 0..31
  const int bh = (jj >> 3) * 8 + xcd;  // 4 bh per XCD
  const int qi = jj & 7;               // 0..7
  const int tau = pair ? qi : 15 - qi;

  const unsigned short* Qb = Qh + (size_t)bh * SEQ * DK;
  const unsigned short* Kb = Kh + (size_t)bh * SEQ * DK;
  const unsigned short* Vb = Vt + (size_t)bh * DK * SEQ;
  const int bq = bh >> 4, hh = bh & 15;
  unsigned short* Mbase = Mg + (size_t)bq * SEQ * DMODEL + hh * DK;

  const int srow = lane >> 3;              // 0..7
  const int sswz = (lane & 7) ^ srow;      // source granule (involution)
  const unsigned short* KsrcB = Kb + (size_t)(w * 8 + srow) * DK + sswz * 8;
  const unsigned short* VsrcB = Vb + (size_t)(w * 8 + srow) * SEQ + sswz * 8;

  const int l7 = l15 & 7;

  const int qbase = tau * 128;
  const int q0w = qbase + w * 16;
  const int nt = 2 * tau + 2;          // even

  bf16x8 qf0 = *reinterpret_cast<const bf16x8*>(Qb + (size_t)(q0w + l15) * DK + l4 * 8);
  bf16x8 qf1 = *reinterpret_cast<const bf16x8*>(Qb + (size_t)(q0w + l15) * DK + 32 + l4 * 8);

  f32x4 o[4] = {};
  float mrow = -__builtin_inff();
  float lrow = 0.0f;

  gload16(KsrcB, &Kl[0][w * 512]);
  gload16(VsrcB, &Vl[0][w * 512]);
  gload16(KsrcB + (size_t)64 * DK, &Kl[1][w * 512]);
  gload16(VsrcB + 64, &Vl[1][w * 512]);

  const int S = nt >> 1;
#pragma unroll 1
  for (int s = 0; s < S; ++s) {
    const int t0 = s << 1;
    const int kbase0 = t0 << 6;

    asm volatile("s_waitcnt vmcnt(0)" ::: "memory");
    __builtin_amdgcn_sched_barrier(0);
    __builtin_amdgcn_s_barrier();
    __builtin_amdgcn_sched_barrier(0);

    if (t0 + 2 < nt) {
      gload16(KsrcB + (size_t)(kbase0 + 128) * DK, &Kl[(t0 + 2) & 3][w * 512]);
      gload16(VsrcB + (kbase0 + 128), &Vl[(t0 + 2) & 3][w * 512]);
      gload16(KsrcB + (size_t)(kbase0 + 192) * DK, &Kl[(t0 + 3) & 3][w * 512]);
      gload16(VsrcB + (kbase0 + 192), &Vl[(t0 + 3) & 3][w * 512]);
    }

#pragma unroll
    for (int u = 0; u < 2; ++u) {
      const int t = t0 + u;
      const int kbase = t << 6;
      if (kbase >= q0w + 16) continue;  // wave-uniform causal skip
      const unsigned short* Kc = Kl[t & 3];
      const unsigned short* Vc = Vl[t & 3];

      f32x4 sc[4];
      __builtin_amdgcn_s_setprio(1);
#pragma unroll
      for (int c = 0; c < 4; ++c) {
        const int krow = c * 16 + l15;
        bf16x8 kf0 = *reinterpret_cast<const bf16x8*>(&Kc[krow * 64 + ((l4 ^ l7) * 8)]);
        bf16x8 kf1 = *reinterpret_cast<const bf16x8*>(&Kc[krow * 64 + (((4 + l4) ^ l7) * 8)]);
        f32x4 z = {0.f, 0.f, 0.f, 0.f};
        z = mfma_bf16(kf0, qf0, z);
        sc[c] = mfma_bf16(kf1, qf1, z);
      }
      __builtin_amdgcn_s_setprio(0);

      if (kbase + 63 > q0w) {
        const int qg = q0w + l15;
#pragma unroll
        for (int c = 0; c < 4; ++c) {
          const int kp = kbase + c * 16 + l4 * 4;
#pragma unroll
          for (int r = 0; r < 4; ++r)
            if (kp + r > qg) sc[c][r] = -__builtin_inff();
        }
      }

      f32x4 mv = sc[0];
#pragma unroll
      for (int c = 1; c < 4; ++c)
#pragma unroll
        for (int r = 0; r < 4; ++r) mv[r] = fmaxf(mv[r], sc[c][r]);
      float pm = fmaxf(fmaxf(mv[0], mv[1]), fmaxf(mv[2], mv[3]));
      if (!__all(pm - mrow <= 8.0f)) {
        pm = fmaxf(pm, __shfl_xor(pm, 16));
        pm = fmaxf(pm, __shfl_xor(pm, 32));
        const float mn = fmaxf(mrow, pm);
        const float al = __builtin_amdgcn_exp2f(mrow - mn);
        mrow = mn;
        lrow *= al;
#pragma unroll
        for (int dd = 0; dd < 4; ++dd)
#pragma unroll
          for (int r = 0; r < 4; ++r) o[dd][r] *= al;
      }
      union PB { bf16x8 v; unsigned int u[4]; } pbv[2];
      f32x4 sv = {0.f, 0.f, 0.f, 0.f};
#pragma unroll
      for (int c = 0; c < 4; ++c) {
        const float p0 = __builtin_amdgcn_exp2f(sc[c][0] - mrow);
        const float p1 = __builtin_amdgcn_exp2f(sc[c][1] - mrow);
        const float p2 = __builtin_amdgcn_exp2f(sc[c][2] - mrow);
        const float p3 = __builtin_amdgcn_exp2f(sc[c][3] - mrow);
        sv[0] += p0; sv[1] += p1; sv[2] += p2; sv[3] += p3;
        pbv[c >> 1].u[(c & 1) * 2 + 0] = cvtpk(p0, p1);
        pbv[c >> 1].u[(c & 1) * 2 + 1] = cvtpk(p2, p3);
      }
      lrow += (sv[0] + sv[1]) + (sv[2] + sv[3]);

      __builtin_amdgcn_s_setprio(1);
#pragma unroll
      for (int dd = 0; dd < 4; ++dd) {
        const int vrow = dd * 16 + l15;
#pragma unroll
        for (int p = 0; p < 2; ++p) {
          const bf16x8 av = *reinterpret_cast<const bf16x8*>(
              &Vc[vrow * 64 + (((p * 4 + l4) ^ l7) * 8)]);
          o[dd] = mfma_bf16(av, pbv[p].v, o[dd]);
        }
      }
      __builtin_amdgcn_s_setprio(0);
    }
  }

  lrow += __shfl_xor(lrow, 16);
  lrow += __shfl_xor(lrow, 32);
  const float inv = __builtin_amdgcn_rcpf(lrow);
  const int s = q0w + l15;
#pragma unroll
  for (int dd = 0; dd < 4; ++dd) {
    union { us4 h; unsigned int u[2]; } pk;
    pk.u[0] = cvtpk(o[dd][0] * inv, o[dd][1] * inv);
    pk.u[1] = cvtpk(o[dd][2] * inv, o[dd][3] * inv);
    *reinterpret_cast<us4*>(&Mbase[(size_t)s * DMODEL + dd * 16 + l4 * 4]) = pk.h;
  }
}

extern "C" void kernel_launch(void* const* d_in, const int* in_sizes, int n_in,
                              void* d_out, int out_size, void* d_ws, size_t ws_size,
                              hipStream_t stream) {
  (void)in_sizes; (void)n_in; (void)out_size;
  if (ws_size < (size_t)64 * (1 << 20)) return;  // need 64MB scratch

  const float* q = (const float*)d_in[0];
  const float* k = (const float*)d_in[1];
  const float* v = (const float*)d_in[2];
  // d_in[3] = mask (causal, hardcoded)
  const float* wq = (const float*)d_in[4];
  const float* wk = (const float*)d_in[5];
  const float* wv = (const float*)d_in[6];
  const float* wo = (const float*)d_in[7];

  char* ws = (char*)d_ws;
  unsigned short* bwq = (unsigned short*)(ws + (size_t)24 * (1 << 20));
  unsigned short* bwk = (unsigned short*)(ws + (size_t)26 * (1 << 20));
  unsigned short* bwv = (unsigned short*)(ws + (size_t)28 * (1 << 20));
  unsigned short* bwo = (unsigned short*)(ws + (size_t)30 * (1 << 20));
  unsigned short* Qh  = (unsigned short*)(ws + (size_t)32 * (1 << 20));
  unsigned short* Kh  = (unsigned short*)(ws + (size_t)40 * (1 << 20));
  unsigned short* Vt  = (unsigned short*)(ws + (size_t)48 * (1 << 20));
  unsigned short* Mg  = (unsigned short*)(ws + (size_t)56 * (1 << 20));

  cvt_w<<<dim3(64, 4), 256, 0, stream>>>(wq, wk, wv, wo, bwq, bwk, bwv, bwo);
  gemm_qk<<<dim3(32, 8, 2), 256, 0, stream>>>(q, k, bwq, bwk, Qh, Kh);
  gemm_v<<<dim3(32, 8), 256, 0, stream>>>(v, bwv, Vt);
  attn_kernel<<<dim3(512), 512, 0, stream>>>(Qh, Kh, Vt, Mg);
  gemm_o<<<dim3(32, 8), 512, 0, stream>>>(Mg, bwo, (float*)d_out);
}

// Round 20
// 119.542 us; speedup vs baseline: 1.1753x; 1.1753x over previous
//
#include <hip/hip_runtime.h>
#include <hip/hip_bf16.h>
#include <stdint.h>

typedef __attribute__((ext_vector_type(4))) float f32x4;
typedef __attribute__((ext_vector_type(8))) __bf16 bf16x8;
typedef __attribute__((ext_vector_type(4))) unsigned short us4;
typedef __attribute__((ext_vector_type(8))) unsigned short us8;

#define SEQ 2048
#define DMODEL 1024
#define NH 16
#define DK 64
#define MTOT 4096  // B*SEQ

__device__ __forceinline__ unsigned short f2bf(float x) {
  union { float f; unsigned int u; } v; v.f = x;
  unsigned int r = v.u + 0x7fffu + ((v.u >> 16) & 1u);
  return (unsigned short)(r >> 16);
}

// pack 2 f32 -> 2 bf16 in one u32 (lo, hi)
__device__ __forceinline__ unsigned int cvtpk(float lo, float hi) {
  unsigned int r;
  asm("v_cvt_pk_bf16_f32 %0, %1, %2" : "=v"(r) : "v"(lo), "v"(hi));
  return r;
}

__device__ __forceinline__ f32x4 mfma_bf16(bf16x8 a, bf16x8 b, f32x4 c) {
  return __builtin_amdgcn_mfma_f32_16x16x32_bf16(a, b, c, 0, 0, 0);
}

__device__ __forceinline__ void gload16(const unsigned short* g, unsigned short* l) {
  __builtin_amdgcn_global_load_lds((__attribute__((address_space(1))) void*)g,
                                   (__attribute__((address_space(3))) void*)l,
                                   16, 0, 0);
}

// ---------------- fp32 -> bf16 conversion (weights only) ----------------
__global__ void cvt_w(const float* __restrict__ s0, const float* __restrict__ s1,
                      const float* __restrict__ s2, const float* __restrict__ s3,
                      unsigned short* __restrict__ d0, unsigned short* __restrict__ d1,
                      unsigned short* __restrict__ d2, unsigned short* __restrict__ d3) {
  const int y = blockIdx.y;
  const float* s = y == 0 ? s0 : y == 1 ? s1 : y == 2 ? s2 : s3;
  unsigned short* d = y == 0 ? d0 : y == 1 ? d1 : y == 2 ? d2 : d3;
  const int n4 = DMODEL * DMODEL / 4;
  const int stride = gridDim.x * blockDim.x;
  for (int i = blockIdx.x * blockDim.x + threadIdx.x; i < n4; i += stride) {
    f32x4 v = reinterpret_cast<const f32x4*>(s)[i];
    us4 o;
    o.x = f2bf(v.x); o.y = f2bf(v.y); o.z = f2bf(v.z); o.w = f2bf(v.w);
    reinterpret_cast<us4*>(d)[i] = o;
  }
}

// ---------------- Q/K GEMM (R10 structure + depth-2 A prefetch) ----------------
__global__ __launch_bounds__(256) void gemm_qk(
    const float* __restrict__ xq, const float* __restrict__ xk,
    const unsigned short* __restrict__ bwq, const unsigned short* __restrict__ bwk,
    unsigned short* __restrict__ Qh, unsigned short* __restrict__ Kh) {
  const int z = blockIdx.z;
  const float* A = z ? xk : xq;
  const unsigned short* B = z ? bwk : bwq;
  unsigned short* out = z ? Kh : Qh;
  const float scale = z ? 1.0f : 0.18033688011112042f;  // (1/8)*log2(e) for Q

  __shared__ __align__(16) unsigned short lA[128 * 32];
  __shared__ __align__(16) unsigned short lB[128 * 32];
  const int tid = threadIdx.x;
  const int lane = tid & 63;
  const int wid = tid >> 6;
  const int l15 = lane & 15, l4 = lane >> 4;
  const int bm = blockIdx.x, bn = blockIdx.y;
  const int wr = wid >> 1, wc = wid & 1;

  f32x4 acc[4][4] = {};

  const int chunk0 = (wid * 2 + 0) * 64 + lane;
  const int chunk1 = (wid * 2 + 1) * 64 + lane;
  const int ar0 = chunk0 >> 2, ac0 = chunk0 & 3;
  const int ar1 = chunk1 >> 2, ac1 = chunk1 & 3;
  const float* gAf0 = A + (size_t)(bm * 128 + ar0) * 1024 + ac0 * 8;
  const float* gAf1 = A + (size_t)(bm * 128 + ar1) * 1024 + ac1 * 8;
  const unsigned short* gB0 = B + (size_t)(bn * 128 + ar0) * 1024 + (ac0 ^ (ar0 & 3)) * 8;
  const unsigned short* gB1 = B + (size_t)(bn * 128 + ar1) * 1024 + (ac1 ^ (ar1 & 3)) * 8;
  unsigned short* wA0 = lA + ar0 * 32 + ((ac0 ^ (ar0 & 3)) * 8);
  unsigned short* wA1 = lA + ar1 * 32 + ((ac1 ^ (ar1 & 3)) * 8);
  unsigned short* lB0 = lB + (wid * 2 + 0) * 512;
  unsigned short* lB1 = lB + (wid * 2 + 1) * 512;

  const int sx = l15 & 3;  // read-side XOR

  f32x4 raP0 = *reinterpret_cast<const f32x4*>(gAf0);
  f32x4 raP1 = *reinterpret_cast<const f32x4*>(gAf0 + 4);
  f32x4 rbP0 = *reinterpret_cast<const f32x4*>(gAf1);
  f32x4 rbP1 = *reinterpret_cast<const f32x4*>(gAf1 + 4);
  f32x4 raQ0 = *reinterpret_cast<const f32x4*>(gAf0 + 32);
  f32x4 raQ1 = *reinterpret_cast<const f32x4*>(gAf0 + 36);
  f32x4 rbQ0 = *reinterpret_cast<const f32x4*>(gAf1 + 32);
  f32x4 rbQ1 = *reinterpret_cast<const f32x4*>(gAf1 + 36);

#define QK_PACK(RA0, RA1, RB0, RB1)                                       \
  {                                                                       \
    union { us8 h; unsigned int u[4]; } p0_, p1_;                         \
    p0_.u[0] = cvtpk(RA0.x, RA0.y); p0_.u[1] = cvtpk(RA0.z, RA0.w);       \
    p0_.u[2] = cvtpk(RA1.x, RA1.y); p0_.u[3] = cvtpk(RA1.z, RA1.w);       \
    p1_.u[0] = cvtpk(RB0.x, RB0.y); p1_.u[1] = cvtpk(RB0.z, RB0.w);       \
    p1_.u[2] = cvtpk(RB1.x, RB1.y); p1_.u[3] = cvtpk(RB1.z, RB1.w);       \
    *reinterpret_cast<us8*>(wA0) = p0_.h;                                 \
    *reinterpret_cast<us8*>(wA1) = p1_.h;                                 \
  }
#define QK_COMPUTE()                                                      \
  {                                                                       \
    bf16x8 af[4], bfr[4];                                                 \
    _Pragma("unroll")                                                     \
    for (int i = 0; i < 4; ++i)                                           \
      af[i] = *reinterpret_cast<const bf16x8*>(                           \
          &lA[(wr * 64 + i * 16 + l15) * 32 + ((l4 ^ sx) * 8)]);          \
    _Pragma("unroll")                                                     \
    for (int j = 0; j < 4; ++j)                                           \
      bfr[j] = *reinterpret_cast<const bf16x8*>(                          \
          &lB[(wc * 64 + j * 16 + l15) * 32 + ((l4 ^ sx) * 8)]);          \
    _Pragma("unroll")                                                     \
    for (int i = 0; i < 4; ++i)                                           \
      _Pragma("unroll")                                                   \
      for (int j = 0; j < 4; ++j)                                         \
        acc[i][j] = mfma_bf16(bfr[j], af[i], acc[i][j]);                  \
  }

#pragma unroll 1
  for (int kt = 0; kt < 1024; kt += 64) {
    __syncthreads();
    QK_PACK(raP0, raP1, rbP0, rbP1);
    gload16(gB0 + kt, lB0);
    gload16(gB1 + kt, lB1);
    __syncthreads();
    if (kt + 64 < 1024) {
      raP0 = *reinterpret_cast<const f32x4*>(gAf0 + kt + 64);
      raP1 = *reinterpret_cast<const f32x4*>(gAf0 + kt + 68);
      rbP0 = *reinterpret_cast<const f32x4*>(gAf1 + kt + 64);
      rbP1 = *reinterpret_cast<const f32x4*>(gAf1 + kt + 68);
    }
    QK_COMPUTE();
    __syncthreads();
    QK_PACK(raQ0, raQ1, rbQ0, rbQ1);
    gload16(gB0 + kt + 32, lB0);
    gload16(gB1 + kt + 32, lB1);
    __syncthreads();
    if (kt + 96 < 1024) {
      raQ0 = *reinterpret_cast<const f32x4*>(gAf0 + kt + 96);
      raQ1 = *reinterpret_cast<const f32x4*>(gAf0 + kt + 100);
      rbQ0 = *reinterpret_cast<const f32x4*>(gAf1 + kt + 96);
      rbQ1 = *reinterpret_cast<const f32x4*>(gAf1 + kt + 100);
    }
    QK_COMPUTE();
  }
#undef QK_PACK
#undef QK_COMPUTE

  const int row0 = bm * 128 + wr * 64;
  const int col0 = bn * 128 + wc * 64;
#pragma unroll
  for (int i = 0; i < 4; ++i) {
    const int m = row0 + i * 16 + l15;
    const int b = m >> 11, s = m & 2047;
#pragma unroll
    for (int j = 0; j < 4; ++j) {
      const int n0 = col0 + j * 16 + l4 * 4;
      const int h = n0 >> 6, dd = n0 & 63;
      union { us4 h4; unsigned int u[2]; } pk;
      pk.u[0] = cvtpk(acc[i][j][0] * scale, acc[i][j][1] * scale);
      pk.u[1] = cvtpk(acc[i][j][2] * scale, acc[i][j][3] * scale);
      *reinterpret_cast<us4*>(&out[(size_t)(b * NH + h) * (SEQ * DK) + s * DK + dd]) = pk.h4;
    }
  }
}

// ---------------- V GEMM (R10 structure + depth-2 A prefetch), V^T PV-permuted ----------
__global__ __launch_bounds__(256) void gemm_v(
    const float* __restrict__ xv, const unsigned short* __restrict__ bwv,
    unsigned short* __restrict__ Vt) {
  __shared__ __align__(16) unsigned short lA[128 * 32];
  __shared__ __align__(16) unsigned short lB[128 * 32];
  const int tid = threadIdx.x;
  const int lane = tid & 63;
  const int wid = tid >> 6;
  const int l15 = lane & 15, l4 = lane >> 4;
  const int bm = blockIdx.x, bn = blockIdx.y;
  const int wr = wid >> 1, wc = wid & 1;

  f32x4 acc[4][4] = {};

  const int chunk0 = (wid * 2 + 0) * 64 + lane;
  const int chunk1 = (wid * 2 + 1) * 64 + lane;
  const int ar0 = chunk0 >> 2, ac0 = chunk0 & 3;
  const int ar1 = chunk1 >> 2, ac1 = chunk1 & 3;
  const float* gAf0 = xv + (size_t)(bm * 128 + ar0) * 1024 + ac0 * 8;
  const float* gAf1 = xv + (size_t)(bm * 128 + ar1) * 1024 + ac1 * 8;
  const unsigned short* gB0 = bwv + (size_t)(bn * 128 + ar0) * 1024 + (ac0 ^ (ar0 & 3)) * 8;
  const unsigned short* gB1 = bwv + (size_t)(bn * 128 + ar1) * 1024 + (ac1 ^ (ar1 & 3)) * 8;
  unsigned short* wA0 = lA + ar0 * 32 + ((ac0 ^ (ar0 & 3)) * 8);
  unsigned short* wA1 = lA + ar1 * 32 + ((ac1 ^ (ar1 & 3)) * 8);
  unsigned short* lB0 = lB + (wid * 2 + 0) * 512;
  unsigned short* lB1 = lB + (wid * 2 + 1) * 512;

  const int sx = l15 & 3;

  f32x4 raP0 = *reinterpret_cast<const f32x4*>(gAf0);
  f32x4 raP1 = *reinterpret_cast<const f32x4*>(gAf0 + 4);
  f32x4 rbP0 = *reinterpret_cast<const f32x4*>(gAf1);
  f32x4 rbP1 = *reinterpret_cast<const f32x4*>(gAf1 + 4);
  f32x4 raQ0 = *reinterpret_cast<const f32x4*>(gAf0 + 32);
  f32x4 raQ1 = *reinterpret_cast<const f32x4*>(gAf0 + 36);
  f32x4 rbQ0 = *reinterpret_cast<const f32x4*>(gAf1 + 32);
  f32x4 rbQ1 = *reinterpret_cast<const f32x4*>(gAf1 + 36);

#define V_PACK(RA0, RA1, RB0, RB1)                                        \
  {                                                                       \
    union { us8 h; unsigned int u[4]; } p0_, p1_;                         \
    p0_.u[0] = cvtpk(RA0.x, RA0.y); p0_.u[1] = cvtpk(RA0.z, RA0.w);       \
    p0_.u[2] = cvtpk(RA1.x, RA1.y); p0_.u[3] = cvtpk(RA1.z, RA1.w);       \
    p1_.u[0] = cvtpk(RB0.x, RB0.y); p1_.u[1] = cvtpk(RB0.z, RB0.w);       \
    p1_.u[2] = cvtpk(RB1.x, RB1.y); p1_.u[3] = cvtpk(RB1.z, RB1.w);       \
    *reinterpret_cast<us8*>(wA0) = p0_.h;                                 \
    *reinterpret_cast<us8*>(wA1) = p1_.h;                                 \
  }
#define V_COMPUTE()                                                       \
  {                                                                       \
    bf16x8 af[4], bfr[4];                                                 \
    _Pragma("unroll")                                                     \
    for (int i = 0; i < 4; ++i)                                           \
      af[i] = *reinterpret_cast<const bf16x8*>(                           \
          &lA[(wr * 64 + i * 16 + l15) * 32 + ((l4 ^ sx) * 8)]);          \
    _Pragma("unroll")                                                     \
    for (int j = 0; j < 4; ++j)                                           \
      bfr[j] = *reinterpret_cast<const bf16x8*>(                          \
          &lB[(wc * 64 + j * 16 + l15) * 32 + ((l4 ^ sx) * 8)]);          \
    _Pragma("unroll")                                                     \
    for (int i = 0; i < 4; ++i)                                           \
      _Pragma("unroll")                                                   \
      for (int j = 0; j < 4; ++j)                                         \
        acc[i][j] = mfma_bf16(af[i], bfr[j], acc[i][j]);                  \
  }

#pragma unroll 1
  for (int kt = 0; kt < 1024; kt += 64) {
    __syncthreads();
    V_PACK(raP0, raP1, rbP0, rbP1);
    gload16(gB0 + kt, lB0);
    gload16(gB1 + kt, lB1);
    __syncthreads();
    if (kt + 64 < 1024) {
      raP0 = *reinterpret_cast<const f32x4*>(gAf0 + kt + 64);
      raP1 = *reinterpret_cast<const f32x4*>(gAf0 + kt + 68);
      rbP0 = *reinterpret_cast<const f32x4*>(gAf1 + kt + 64);
      rbP1 = *reinterpret_cast<const f32x4*>(gAf1 + kt + 68);
    }
    V_COMPUTE();
    __syncthreads();
    V_PACK(raQ0, raQ1, rbQ0, rbQ1);
    gload16(gB0 + kt + 32, lB0);
    gload16(gB1 + kt + 32, lB1);
    __syncthreads();
    if (kt + 96 < 1024) {
      raQ0 = *reinterpret_cast<const f32x4*>(gAf0 + kt + 96);
      raQ1 = *reinterpret_cast<const f32x4*>(gAf0 + kt + 100);
      rbQ0 = *reinterpret_cast<const f32x4*>(gAf1 + kt + 96);
      rbQ1 = *reinterpret_cast<const f32x4*>(gAf1 + kt + 100);
    }
    V_COMPUTE();
  }
#undef V_PACK
#undef V_COMPUTE

  const int row0 = bm * 128 + wr * 64;
  const int col0 = bn * 128 + wc * 64;
#pragma unroll
  for (int i = 0; i < 4; ++i) {
    const int m0 = row0 + i * 16 + l4 * 4;
    const int b = m0 >> 11, s0 = m0 & 2047;
    const int g = (s0 >> 2) & 7;
    const int col = (s0 & ~31) + ((g & 3) << 3) + ((g >> 2) << 2);
#pragma unroll
    for (int j = 0; j < 4; ++j) {
      const int n = col0 + j * 16 + l15;
      const int h = n >> 6, dd = n & 63;
      union { us4 h4; unsigned int u[2]; } pk;
      pk.u[0] = cvtpk(acc[i][j][0], acc[i][j][1]);
      pk.u[1] = cvtpk(acc[i][j][2], acc[i][j][3]);
      *reinterpret_cast<us4*>(&Vt[(size_t)(b * NH + h) * (DK * SEQ) + dd * SEQ + col]) = pk.h4;
    }
  }
}

// ---------------- output-projection GEMM: 8 waves, BK=64, 3-buffer pipeline ----------------
__global__ __launch_bounds__(512) void gemm_o(const unsigned short* __restrict__ A,
                                              const unsigned short* __restrict__ B,
                                              float* __restrict__ out) {
  __shared__ __align__(16) unsigned short lA3[3][128 * 64];
  __shared__ __align__(16) unsigned short lB3[3][128 * 64];

  const int tid = threadIdx.x;
  const int lane = tid & 63, wid = tid >> 6;
  const int l15 = lane & 15, l4 = lane >> 4;
  const int bm = blockIdx.x, bn = blockIdx.y;
  const int wr = wid >> 1, wc = wid & 1;

  f32x4 acc[2][4] = {};

  const int r8 = lane >> 3, c8 = lane & 7;
  const unsigned short* gAs[2];
  const unsigned short* gBs[2];
  int dstoff[2];
#pragma unroll
  for (int is = 0; is < 2; ++is) {
    const int rbase = is * 64 + wid * 8;
    gAs[is] = A + (size_t)(bm * 128 + rbase + r8) * 1024 + (c8 ^ r8) * 8;
    gBs[is] = B + (size_t)(bn * 128 + rbase + r8) * 1024 + (c8 ^ r8) * 8;
    dstoff[is] = rbase * 64;
  }

#define STAGE_O(t, buf)                                         \
  {                                                             \
    const int kb = (t) * 64;                                    \
    gload16(gAs[0] + kb, &lA3[buf][dstoff[0]]);                 \
    gload16(gAs[1] + kb, &lA3[buf][dstoff[1]]);                 \
    gload16(gBs[0] + kb, &lB3[buf][dstoff[0]]);                 \
    gload16(gBs[1] + kb, &lB3[buf][dstoff[1]]);                 \
  }

  STAGE_O(0, 0);
  STAGE_O(1, 1);

#pragma unroll 1
  for (int t = 0; t < 16; ++t) {
    if (t + 1 < 16) {
      asm volatile("s_waitcnt vmcnt(4)" ::: "memory");
    } else {
      asm volatile("s_waitcnt vmcnt(0)" ::: "memory");
    }
    __builtin_amdgcn_sched_barrier(0);
    __builtin_amdgcn_s_barrier();
    __builtin_amdgcn_sched_barrier(0);

    if (t + 2 < 16) {
      const int pb = (t + 2) % 3;
      STAGE_O(t + 2, pb);
    }

    const unsigned short* La = lA3[t % 3];
    const unsigned short* Lb = lB3[t % 3];
#pragma unroll
    for (int kk = 0; kk < 2; ++kk) {
      bf16x8 af[2], bf[4];
#pragma unroll
      for (int i = 0; i < 2; ++i) {
        const int row = wr * 32 + i * 16 + l15;
        af[i] = *reinterpret_cast<const bf16x8*>(
            &La[row * 64 + (((kk * 4 + l4) ^ (l15 & 7)) * 8)]);
      }
#pragma unroll
      for (int j = 0; j < 4; ++j) {
        const int row = wc * 64 + j * 16 + l15;
        bf[j] = *reinterpret_cast<const bf16x8*>(
            &Lb[row * 64 + (((kk * 4 + l4) ^ (l15 & 7)) * 8)]);
      }
#pragma unroll
      for (int i = 0; i < 2; ++i)
#pragma unroll
        for (int j = 0; j < 4; ++j)
          acc[i][j] = mfma_bf16(bf[j], af[i], acc[i][j]);  // SWAPPED
    }
  }
#undef STAGE_O

  const int row0 = bm * 128 + wr * 32;
  const int col0 = bn * 128 + wc * 64;
#pragma unroll
  for (int i = 0; i < 2; ++i) {
    const int m = row0 + i * 16 + l15;
#pragma unroll
    for (int j = 0; j < 4; ++j) {
      const int n0 = col0 + j * 16 + l4 * 4;
      *reinterpret_cast<f32x4*>(&out[(size_t)m * DMODEL + n0]) = acc[i][j];
    }
  }
}

// ---------------- causal flash attention v9: 512 blocks, balanced split-pair ----------------
__global__ __launch_bounds__(512, 2) void attn_kernel(const unsigned short* __restrict__ Qh,
                                                      const unsigned short* __restrict__ Kh,
                                                      const unsigned short* __restrict__ Vt,
                                                      unsigned short* __restrict__ Mg) {
  __shared__ __align__(16) unsigned short Kl[4][64 * 64];
  __shared__ __align__(16) unsigned short Vl[4][64 * 64];

  const int tid = threadIdx.x;
  const int lane = tid & 63;
  const int w = tid >> 6;
  const int l15 = lane & 15, l4 = lane >> 4;

  const int d = blockIdx.x;            // 0..511
  const int base = d & 255;            // CU slot (round-robin assumption)
  const int pair = d >> 8;             // 0: long tile, 1: short tile
  const int xcd = base & 7;
  const int jj = base >> 3;            // 0..31
  const int bh = (jj >> 3) * 8 + xcd;  // 4 bh per XCD
  const int qi = jj & 7;               // 0..7
  const int tau = pair ? qi : 15 - qi;

  const unsigned short* Qb = Qh + (size_t)bh * SEQ * DK;
  const unsigned short* Kb = Kh + (size_t)bh * SEQ * DK;
  const unsigned short* Vb = Vt + (size_t)bh * DK * SEQ;
  const int bq = bh >> 4, hh = bh & 15;
  unsigned short* Mbase = Mg + (size_t)bq * SEQ * DMODEL + hh * DK;

  const int srow = lane >> 3;              // 0..7
  const int sswz = (lane & 7) ^ srow;      // source granule (involution)
  const unsigned short* KsrcB = Kb + (size_t)(w * 8 + srow) * DK + sswz * 8;
  const unsigned short* VsrcB = Vb + (size_t)(w * 8 + srow) * SEQ + sswz * 8;

  const int l7 = l15 & 7;

  const int qbase = tau * 128;
  const int q0w = qbase + w * 16;
  const int nt = 2 * tau + 2;          // even

  bf16x8 qf0 = *reinterpret_cast<const bf16x8*>(Qb + (size_t)(q0w + l15) * DK + l4 * 8);
  bf16x8 qf1 = *reinterpret_cast<const bf16x8*>(Qb + (size_t)(q0w + l15) * DK + 32 + l4 * 8);

  f32x4 o[4] = {};
  float mrow = -__builtin_inff();
  float lrow = 0.0f;

  gload16(KsrcB, &Kl[0][w * 512]);
  gload16(VsrcB, &Vl[0][w * 512]);
  gload16(KsrcB + (size_t)64 * DK, &Kl[1][w * 512]);
  gload16(VsrcB + 64, &Vl[1][w * 512]);

  const int S = nt >> 1;
#pragma unroll 1
  for (int s = 0; s < S; ++s) {
    const int t0 = s << 1;
    const int kbase0 = t0 << 6;

    asm volatile("s_waitcnt vmcnt(0)" ::: "memory");
    __builtin_amdgcn_sched_barrier(0);
    __builtin_amdgcn_s_barrier();
    __builtin_amdgcn_sched_barrier(0);

    if (t0 + 2 < nt) {
      gload16(KsrcB + (size_t)(kbase0 + 128) * DK, &Kl[(t0 + 2) & 3][w * 512]);
      gload16(VsrcB + (kbase0 + 128), &Vl[(t0 + 2) & 3][w * 512]);
      gload16(KsrcB + (size_t)(kbase0 + 192) * DK, &Kl[(t0 + 3) & 3][w * 512]);
      gload16(VsrcB + (kbase0 + 192), &Vl[(t0 + 3) & 3][w * 512]);
    }

#pragma unroll
    for (int u = 0; u < 2; ++u) {
      const int t = t0 + u;
      const int kbase = t << 6;
      if (kbase >= q0w + 16) continue;  // wave-uniform causal skip
      const unsigned short* Kc = Kl[t & 3];
      const unsigned short* Vc = Vl[t & 3];

      f32x4 sc[4];
      __builtin_amdgcn_s_setprio(1);
#pragma unroll
      for (int c = 0; c < 4; ++c) {
        const int krow = c * 16 + l15;
        bf16x8 kf0 = *reinterpret_cast<const bf16x8*>(&Kc[krow * 64 + ((l4 ^ l7) * 8)]);
        bf16x8 kf1 = *reinterpret_cast<const bf16x8*>(&Kc[krow * 64 + (((4 + l4) ^ l7) * 8)]);
        f32x4 z = {0.f, 0.f, 0.f, 0.f};
        z = mfma_bf16(kf0, qf0, z);
        sc[c] = mfma_bf16(kf1, qf1, z);
      }
      __builtin_amdgcn_s_setprio(0);

      if (kbase + 63 > q0w) {
        const int qg = q0w + l15;
#pragma unroll
        for (int c = 0; c < 4; ++c) {
          const int kp = kbase + c * 16 + l4 * 4;
#pragma unroll
          for (int r = 0; r < 4; ++r)
            if (kp + r > qg) sc[c][r] = -__builtin_inff();
        }
      }

      f32x4 mv = sc[0];
#pragma unroll
      for (int c = 1; c < 4; ++c)
#pragma unroll
        for (int r = 0; r < 4; ++r) mv[r] = fmaxf(mv[r], sc[c][r]);
      float pm = fmaxf(fmaxf(mv[0], mv[1]), fmaxf(mv[2], mv[3]));
      if (!__all(pm - mrow <= 8.0f)) {
        pm = fmaxf(pm, __shfl_xor(pm, 16));
        pm = fmaxf(pm, __shfl_xor(pm, 32));
        const float mn = fmaxf(mrow, pm);
        const float al = __builtin_amdgcn_exp2f(mrow - mn);
        mrow = mn;
        lrow *= al;
#pragma unroll
        for (int dd = 0; dd < 4; ++dd)
#pragma unroll
          for (int r = 0; r < 4; ++r) o[dd][r] *= al;
      }
      union PB { bf16x8 v; unsigned int u[4]; } pbv[2];
      f32x4 sv = {0.f, 0.f, 0.f, 0.f};
#pragma unroll
      for (int c = 0; c < 4; ++c) {
        const float p0 = __builtin_amdgcn_exp2f(sc[c][0] - mrow);
        const float p1 = __builtin_amdgcn_exp2f(sc[c][1] - mrow);
        const float p2 = __builtin_amdgcn_exp2f(sc[c][2] - mrow);
        const float p3 = __builtin_amdgcn_exp2f(sc[c][3] - mrow);
        sv[0] += p0; sv[1] += p1; sv[2] += p2; sv[3] += p3;
        pbv[c >> 1].u[(c & 1) * 2 + 0] = cvtpk(p0, p1);
        pbv[c >> 1].u[(c & 1) * 2 + 1] = cvtpk(p2, p3);
      }
      lrow += (sv[0] + sv[1]) + (sv[2] + sv[3]);

      __builtin_amdgcn_s_setprio(1);
#pragma unroll
      for (int dd = 0; dd < 4; ++dd) {
        const int vrow = dd * 16 + l15;
#pragma unroll
        for (int p = 0; p < 2; ++p) {
          const bf16x8 av = *reinterpret_cast<const bf16x8*>(
              &Vc[vrow * 64 + (((p * 4 + l4) ^ l7) * 8)]);
          o[dd] = mfma_bf16(av, pbv[p].v, o[dd]);
        }
      }
      __builtin_amdgcn_s_setprio(0);
    }
  }

  lrow += __shfl_xor(lrow, 16);
  lrow += __shfl_xor(lrow, 32);
  const float inv = __builtin_amdgcn_rcpf(lrow);
  const int s = q0w + l15;
#pragma unroll
  for (int dd = 0; dd < 4; ++dd) {
    union { us4 h; unsigned int u[2]; } pk;
    pk.u[0] = cvtpk(o[dd][0] * inv, o[dd][1] * inv);
    pk.u[1] = cvtpk(o[dd][2] * inv, o[dd][3] * inv);
    *reinterpret_cast<us4*>(&Mbase[(size_t)s * DMODEL + dd * 16 + l4 * 4]) = pk.h;
  }
}

extern "C" void kernel_launch(void* const* d_in, const int* in_sizes, int n_in,
                              void* d_out, int out_size, void* d_ws, size_t ws_size,
                              hipStream_t stream) {
  (void)in_sizes; (void)n_in; (void)out_size;
  if (ws_size < (size_t)64 * (1 << 20)) return;  // need 64MB scratch

  const float* q = (const float*)d_in[0];
  const float* k = (const float*)d_in[1];
  const float* v = (const float*)d_in[2];
  // d_in[3] = mask (causal, hardcoded)
  const float* wq = (const float*)d_in[4];
  const float* wk = (const float*)d_in[5];
  const float* wv = (const float*)d_in[6];
  const float* wo = (const float*)d_in[7];

  char* ws = (char*)d_ws;
  unsigned short* bwq = (unsigned short*)(ws + (size_t)24 * (1 << 20));
  unsigned short* bwk = (unsigned short*)(ws + (size_t)26 * (1 << 20));
  unsigned short* bwv = (unsigned short*)(ws + (size_t)28 * (1 << 20));
  unsigned short* bwo = (unsigned short*)(ws + (size_t)30 * (1 << 20));
  unsigned short* Qh  = (unsigned short*)(ws + (size_t)32 * (1 << 20));
  unsigned short* Kh  = (unsigned short*)(ws + (size_t)40 * (1 << 20));
  unsigned short* Vt  = (unsigned short*)(ws + (size_t)48 * (1 << 20));
  unsigned short* Mg  = (unsigned short*)(ws + (size_t)56 * (1 << 20));

  cvt_w<<<dim3(64, 4), 256, 0, stream>>>(wq, wk, wv, wo, bwq, bwk, bwv, bwo);
  gemm_qk<<<dim3(32, 8, 2), 256, 0, stream>>>(q, k, bwq, bwk, Qh, Kh);
  gemm_v<<<dim3(32, 8), 256, 0, stream>>>(v, bwv, Vt);
  attn_kernel<<<dim3(512), 512, 0, stream>>>(Qh, Kh, Vt, Mg);
  gemm_o<<<dim3(32, 8), 512, 0, stream>>>(Mg, bwo, (float*)d_out);
}